// Round 1
// baseline (4954.670 us; speedup 1.0000x reference)
//
#include <hip/hip_runtime.h>
#include <hip/hip_bf16.h>

#define T_TOKENS 16384
#define DM 1024
#define DFF 4096
#define NEXP 8
#define SLAB 512
#define NSLABS (DFF / SLAB)

#define BM 64
#define BN 64
#define BK 16

// ---------------- router: one wave per token ----------------
__global__ __launch_bounds__(256) void router_kernel(
    const float* __restrict__ x, const float* __restrict__ Wr,
    const float* __restrict__ br, int* __restrict__ eidx,
    float* __restrict__ wgt, int* __restrict__ count) {
  int wave = threadIdx.x >> 6;
  int lane = threadIdx.x & 63;
  int t = blockIdx.x * 4 + wave;
  if (t >= T_TOKENS) return;

  float acc[8];
#pragma unroll
  for (int e = 0; e < 8; e++) acc[e] = 0.f;

  const float* xr = x + (size_t)t * DM;
  for (int k = lane; k < DM; k += 64) {
    float xv = xr[k];
    const float4* w4 = (const float4*)(Wr + (size_t)k * 8);
    float4 w0 = w4[0];
    float4 w1 = w4[1];
    acc[0] += xv * w0.x; acc[1] += xv * w0.y;
    acc[2] += xv * w0.z; acc[3] += xv * w0.w;
    acc[4] += xv * w1.x; acc[5] += xv * w1.y;
    acc[6] += xv * w1.z; acc[7] += xv * w1.w;
  }
#pragma unroll
  for (int e = 0; e < 8; e++) {
#pragma unroll
    for (int m = 32; m > 0; m >>= 1) acc[e] += __shfl_xor(acc[e], m, 64);
  }
  if (lane == 0) {
    float lg[8];
    float mx = -1e30f;
#pragma unroll
    for (int e = 0; e < 8; e++) {
      lg[e] = acc[e] + br[e];
      mx = fmaxf(mx, lg[e]);
    }
    float s = 0.f;
#pragma unroll
    for (int e = 0; e < 8; e++) s += expf(lg[e] - mx);
    int am = 0;
    float best = lg[0];
#pragma unroll
    for (int e = 1; e < 8; e++) {
      if (lg[e] > best) { best = lg[e]; am = e; }
    }
    eidx[t] = am;
    wgt[t] = expf(best - mx) / s;
    atomicAdd(&count[am], 1);
  }
}

// ---------------- exclusive scan over 8 counts ----------------
__global__ void scan_kernel(const int* __restrict__ count, int* __restrict__ offsets,
                            int* __restrict__ cursor) {
  if (threadIdx.x == 0) {
    int run = 0;
    for (int e = 0; e < NEXP; e++) {
      offsets[e] = run;
      cursor[e] = run;
      run += count[e];
    }
    offsets[NEXP] = run;
  }
}

// ---------------- scatter token ids into per-expert lists ----------------
__global__ __launch_bounds__(256) void scatter_kernel(
    const int* __restrict__ eidx, int* __restrict__ cursor, int* __restrict__ perm) {
  int t = blockIdx.x * 256 + threadIdx.x;
  if (t < T_TOKENS) {
    int e = eidx[t];
    int pos = atomicAdd(&cursor[e], 1);
    perm[pos] = t;
  }
}

// ---------------- grouped GEMM1: h = relu(Xg @ W1e + b1e), one d_ff slab ----------------
__global__ __launch_bounds__(256) void gemm1_kernel(
    const float* __restrict__ x, const float* __restrict__ W1,
    const float* __restrict__ b1, const int* __restrict__ perm,
    const int* __restrict__ offsets, __hip_bfloat16* __restrict__ h, int slab) {
  int e = blockIdx.z;
  int beg = offsets[e];
  int rows = offsets[e + 1] - beg;
  int row0 = blockIdx.y * BM;
  if (row0 >= rows) return;
  int col0 = blockIdx.x * BN;       // within slab
  int gcol0 = slab * SLAB + col0;   // within d_ff

  __shared__ float As[BK][BM + 4];
  __shared__ float Bs[BK][BN + 4];
  __shared__ int toks[BM];

  int tid = threadIdx.x;
  if (tid < BM) {
    int r = row0 + tid;
    toks[tid] = (r < rows) ? perm[beg + r] : -1;
  }
  __syncthreads();

  int tx = tid & 15, ty = tid >> 4;
  float c[4][4] = {};

  const float* W1e = W1 + (size_t)e * DM * DFF + gcol0;

  for (int k0 = 0; k0 < DM; k0 += BK) {
#pragma unroll
    for (int i = 0; i < 4; i++) {
      int idx = tid + i * 256;
      int m = idx >> 4, k = idx & 15;
      int tok = toks[m];
      As[k][m] = (tok >= 0) ? x[(size_t)tok * DM + k0 + k] : 0.f;
    }
#pragma unroll
    for (int i = 0; i < 4; i++) {
      int idx = tid + i * 256;
      int k = idx >> 6, j = idx & 63;
      Bs[k][j] = W1e[(size_t)(k0 + k) * DFF + j];
    }
    __syncthreads();
#pragma unroll
    for (int k = 0; k < BK; k++) {
      float a[4], b[4];
#pragma unroll
      for (int i = 0; i < 4; i++) a[i] = As[k][ty * 4 + i];
#pragma unroll
      for (int j = 0; j < 4; j++) b[j] = Bs[k][tx * 4 + j];
#pragma unroll
      for (int i = 0; i < 4; i++)
#pragma unroll
        for (int j = 0; j < 4; j++) c[i][j] += a[i] * b[j];
    }
    __syncthreads();
  }

#pragma unroll
  for (int i = 0; i < 4; i++) {
    int m = ty * 4 + i;
    if (row0 + m < rows) {
      size_t hrow = (size_t)(beg + row0 + m) * SLAB;
#pragma unroll
      for (int j = 0; j < 4; j++) {
        int cs = col0 + tx * 4 + j;
        float v = c[i][j] + b1[(size_t)e * DFF + slab * SLAB + cs];
        h[hrow + cs] = __float2bfloat16(fmaxf(v, 0.f));
      }
    }
  }
}

// ---------------- grouped GEMM2: out += Hslab @ W2e_slab ----------------
__global__ __launch_bounds__(256) void gemm2_kernel(
    const __hip_bfloat16* __restrict__ h, const float* __restrict__ W2,
    const int* __restrict__ perm, const int* __restrict__ offsets,
    float* __restrict__ out, int slab) {
  int e = blockIdx.z;
  int beg = offsets[e];
  int rows = offsets[e + 1] - beg;
  int row0 = blockIdx.y * BM;
  if (row0 >= rows) return;
  int col0 = blockIdx.x * BN;  // within d_model

  __shared__ float As[BK][BM + 4];
  __shared__ float Bs[BK][BN + 4];
  __shared__ int toks[BM];

  int tid = threadIdx.x;
  if (tid < BM) {
    int r = row0 + tid;
    toks[tid] = (r < rows) ? perm[beg + r] : -1;
  }
  __syncthreads();

  int tx = tid & 15, ty = tid >> 4;
  float c[4][4] = {};

  const float* W2e = W2 + (size_t)e * DFF * DM + (size_t)slab * SLAB * DM + col0;

  for (int k0 = 0; k0 < SLAB; k0 += BK) {
#pragma unroll
    for (int i = 0; i < 4; i++) {
      int idx = tid + i * 256;
      int m = idx >> 4, k = idx & 15;
      As[k][m] = (row0 + m < rows)
                     ? __bfloat162float(h[(size_t)(beg + row0 + m) * SLAB + k0 + k])
                     : 0.f;
    }
#pragma unroll
    for (int i = 0; i < 4; i++) {
      int idx = tid + i * 256;
      int k = idx >> 6, j = idx & 63;
      Bs[k][j] = W2e[(size_t)(k0 + k) * DM + j];
    }
    __syncthreads();
#pragma unroll
    for (int k = 0; k < BK; k++) {
      float a[4], b[4];
#pragma unroll
      for (int i = 0; i < 4; i++) a[i] = As[k][ty * 4 + i];
#pragma unroll
      for (int j = 0; j < 4; j++) b[j] = Bs[k][tx * 4 + j];
#pragma unroll
      for (int i = 0; i < 4; i++)
#pragma unroll
        for (int j = 0; j < 4; j++) c[i][j] += a[i] * b[j];
    }
    __syncthreads();
  }

#pragma unroll
  for (int i = 0; i < 4; i++) {
    int m = ty * 4 + i;
    if (row0 + m < rows) {
      int t = toks[m];
      size_t orow = (size_t)t * DM + col0;
#pragma unroll
      for (int j = 0; j < 4; j++) out[orow + tx * 4 + j] += c[i][j];
    }
  }
}

// ---------------- finalize: out = (out + b2[e]) * weight ----------------
__global__ __launch_bounds__(256) void finalize_kernel(
    float* __restrict__ out, const float* __restrict__ b2,
    const int* __restrict__ eidx, const float* __restrict__ wgt) {
  int idx = blockIdx.x * 256 + threadIdx.x;
  int t = idx >> 10;
  int n = idx & 1023;
  int e = eidx[t];
  out[idx] = (out[idx] + b2[(size_t)e * DM + n]) * wgt[t];
}

extern "C" void kernel_launch(void* const* d_in, const int* in_sizes, int n_in,
                              void* d_out, int out_size, void* d_ws, size_t ws_size,
                              hipStream_t stream) {
  (void)in_sizes; (void)n_in; (void)out_size; (void)ws_size;
  const float* x  = (const float*)d_in[0];
  const float* Wr = (const float*)d_in[1];
  const float* br = (const float*)d_in[2];
  const float* W1 = (const float*)d_in[3];
  const float* b1 = (const float*)d_in[4];
  const float* W2 = (const float*)d_in[5];
  const float* b2 = (const float*)d_in[6];
  float* out = (float*)d_out;

  char* ws = (char*)d_ws;
  int*   eidx    = (int*)(ws + 0);            // 64 KB
  float* wgt     = (float*)(ws + 65536);      // 64 KB
  int*   count   = (int*)(ws + 131072);       // 32 B
  int*   offsets = (int*)(ws + 131136);       // 36 B
  int*   cursor  = (int*)(ws + 131200);       // 32 B
  int*   perm    = (int*)(ws + 131328);       // 64 KB
  __hip_bfloat16* h = (__hip_bfloat16*)(ws + 262144);  // 16 MB (T x SLAB bf16)

  hipMemsetAsync(count, 0, 32, stream);
  hipMemsetAsync(out, 0, (size_t)T_TOKENS * DM * sizeof(float), stream);

  router_kernel<<<T_TOKENS / 4, 256, 0, stream>>>(x, Wr, br, eidx, wgt, count);
  scan_kernel<<<1, 64, 0, stream>>>(count, offsets, cursor);
  scatter_kernel<<<T_TOKENS / 256, 256, 0, stream>>>(eidx, cursor, perm);

  for (int s = 0; s < NSLABS; s++) {
    gemm1_kernel<<<dim3(SLAB / BN, T_TOKENS / BM, NEXP), 256, 0, stream>>>(
        x, W1, b1, perm, offsets, h, s);
    gemm2_kernel<<<dim3(DM / BN, T_TOKENS / BM, NEXP), 256, 0, stream>>>(
        h, W2, perm, offsets, out, s);
  }
  finalize_kernel<<<(T_TOKENS * DM) / 256, 256, 0, stream>>>(out, b2, eidx, wgt);
}

// Round 2
// 1257.744 us; speedup vs baseline: 3.9393x; 3.9393x over previous
//
#include <hip/hip_runtime.h>
#include <hip/hip_bf16.h>

#define T_TOKENS 16384
#define DM 1024
#define DFF 4096
#define NEXP 8
#define SLAB 2048
#define NSLABS (DFF / SLAB)

#define BM 128
#define BN 128
#define BKS 32

typedef unsigned short ushort_t;
typedef __attribute__((ext_vector_type(8))) __bf16 bf16x8;
typedef __attribute__((ext_vector_type(4))) float f32x4;

__device__ __forceinline__ void async16(void* lds, const void* g) {
  __builtin_amdgcn_global_load_lds(
      (__attribute__((address_space(1))) void*)(void*)g,
      (__attribute__((address_space(3))) void*)lds, 16, 0, 0);
}

__device__ __forceinline__ ushort_t f2bf(float f) {
  union { float f; unsigned u; } v;
  v.f = f;
  unsigned r = v.u + 0x7FFF + ((v.u >> 16) & 1);
  return (ushort_t)(r >> 16);
}

// ---------------- router: one wave per token ----------------
__global__ __launch_bounds__(256) void router_kernel(
    const float* __restrict__ x, const float* __restrict__ Wr,
    const float* __restrict__ br, int* __restrict__ eidx,
    float* __restrict__ wgt, int* __restrict__ count) {
  int wave = threadIdx.x >> 6;
  int lane = threadIdx.x & 63;
  int t = blockIdx.x * 4 + wave;
  if (t >= T_TOKENS) return;

  float acc[8];
#pragma unroll
  for (int e = 0; e < 8; e++) acc[e] = 0.f;

  const float* xr = x + (size_t)t * DM;
  for (int k = lane; k < DM; k += 64) {
    float xv = xr[k];
    const float4* w4 = (const float4*)(Wr + (size_t)k * 8);
    float4 w0 = w4[0];
    float4 w1 = w4[1];
    acc[0] += xv * w0.x; acc[1] += xv * w0.y;
    acc[2] += xv * w0.z; acc[3] += xv * w0.w;
    acc[4] += xv * w1.x; acc[5] += xv * w1.y;
    acc[6] += xv * w1.z; acc[7] += xv * w1.w;
  }
#pragma unroll
  for (int e = 0; e < 8; e++) {
#pragma unroll
    for (int m = 32; m > 0; m >>= 1) acc[e] += __shfl_xor(acc[e], m, 64);
  }
  if (lane == 0) {
    float lg[8];
    float mx = -1e30f;
#pragma unroll
    for (int e = 0; e < 8; e++) {
      lg[e] = acc[e] + br[e];
      mx = fmaxf(mx, lg[e]);
    }
    float s = 0.f;
#pragma unroll
    for (int e = 0; e < 8; e++) s += expf(lg[e] - mx);
    int am = 0;
    float best = lg[0];
#pragma unroll
    for (int e = 1; e < 8; e++) {
      if (lg[e] > best) { best = lg[e]; am = e; }
    }
    eidx[t] = am;
    wgt[t] = expf(best - mx) / s;
    atomicAdd(&count[am], 1);
  }
}

// ---------------- exclusive scan over 8 counts ----------------
__global__ void scan_kernel(const int* __restrict__ count, int* __restrict__ offsets,
                            int* __restrict__ cursor) {
  if (threadIdx.x == 0) {
    int run = 0;
    for (int e = 0; e < NEXP; e++) {
      offsets[e] = run;
      cursor[e] = run;
      run += count[e];
    }
    offsets[NEXP] = run;
  }
}

// ---------------- scatter token ids into per-expert lists ----------------
__global__ __launch_bounds__(256) void scatter_kernel(
    const int* __restrict__ eidx, int* __restrict__ cursor, int* __restrict__ perm) {
  int t = blockIdx.x * 256 + threadIdx.x;
  if (t < T_TOKENS) {
    int e = eidx[t];
    int pos = atomicAdd(&cursor[e], 1);
    perm[pos] = t;
  }
}

// ---------------- gather x rows into expert order, fp32 -> bf16 ----------------
__global__ __launch_bounds__(256) void gather_x_kernel(
    const float* __restrict__ x, const int* __restrict__ perm,
    ushort_t* __restrict__ xg) {
  int g = blockIdx.x;
  int tok = perm[g];
  int tid = threadIdx.x;
  float4 v = ((const float4*)(x + (size_t)tok * DM))[tid];
  ushort4 o;
  o.x = f2bf(v.x); o.y = f2bf(v.y); o.z = f2bf(v.z); o.w = f2bf(v.w);
  ((ushort4*)(xg + (size_t)g * DM))[tid] = o;
}

// ---------------- transpose+convert: W [E][R][C] fp32 -> WT [E][C][R] bf16 ----------------
__global__ __launch_bounds__(256) void convT_kernel(
    const float* __restrict__ W, ushort_t* __restrict__ WT, int R, int C) {
  __shared__ float t[64][65];
  int e = blockIdx.z;
  int r0 = blockIdx.y << 6, c0 = blockIdx.x << 6;
  int tid = threadIdx.x;
  const float* Wp = W + (size_t)e * R * C;
#pragma unroll
  for (int i = 0; i < 4; i++) {
    int r = (tid >> 4) + i * 16;
    int c = (tid & 15) * 4;
    float4 v = *(const float4*)(Wp + (size_t)(r0 + r) * C + c0 + c);
    t[r][c] = v.x; t[r][c + 1] = v.y; t[r][c + 2] = v.z; t[r][c + 3] = v.w;
  }
  __syncthreads();
  ushort_t* Op = WT + (size_t)e * R * C;
#pragma unroll
  for (int i = 0; i < 4; i++) {
    int c = (tid >> 4) + i * 16;
    int r = (tid & 15) * 4;
    ushort4 o;
    o.x = f2bf(t[r][c]);
    o.y = f2bf(t[r + 1][c]);
    o.z = f2bf(t[r + 2][c]);
    o.w = f2bf(t[r + 3][c]);
    *(ushort4*)(Op + (size_t)(c0 + c) * R + r0 + r) = o;
  }
}

// ---------------- MFMA GEMM1: h = relu(Xg @ W1 + b1), one d_ff slab ----------------
__global__ __launch_bounds__(256) void gemm1_kernel(
    const ushort_t* __restrict__ xg, const ushort_t* __restrict__ W1T,
    const float* __restrict__ b1, const int* __restrict__ offsets,
    ushort_t* __restrict__ h, int slab) {
  int e = blockIdx.z;
  int beg = offsets[e];
  int rows = offsets[e + 1] - beg;
  int row0 = blockIdx.y * BM;
  if (row0 >= rows) return;
  int col0 = blockIdx.x * BN;       // within slab
  int gcol0 = slab * SLAB + col0;   // within DFF

  __shared__ ushort_t As[BM * BKS];
  __shared__ ushort_t Bs[BN * BKS];

  int tid = threadIdx.x;
  int wave = tid >> 6, lane = tid & 63;
  int wm = (wave & 1) * 64, wn = (wave >> 1) * 64;
  int lr = lane & 15;
  int kf = (lane >> 4) * 8;

  f32x4 acc[4][4] = {};

  const ushort_t* Ap = xg + (size_t)(beg + row0) * DM;
  const ushort_t* Bp = W1T + ((size_t)e * DFF + gcol0) * DM;

  for (int k0 = 0; k0 < DM; k0 += BKS) {
#pragma unroll
    for (int it = 0; it < 2; it++) {
      int idx = it * 256 + tid;
      int rr = idx >> 2, pp = idx & 3;
      async16(As + idx * 8, Ap + (size_t)rr * DM + k0 + pp * 8);
      async16(Bs + idx * 8, Bp + (size_t)rr * DM + k0 + pp * 8);
    }
    __syncthreads();
    bf16x8 af[4], bfr[4];
#pragma unroll
    for (int i = 0; i < 4; i++)
      af[i] = *(const bf16x8*)(As + (wm + i * 16 + lr) * BKS + kf);
#pragma unroll
    for (int j = 0; j < 4; j++)
      bfr[j] = *(const bf16x8*)(Bs + (wn + j * 16 + lr) * BKS + kf);
#pragma unroll
    for (int i = 0; i < 4; i++)
#pragma unroll
      for (int j = 0; j < 4; j++)
        acc[i][j] = __builtin_amdgcn_mfma_f32_16x16x32_bf16(af[i], bfr[j], acc[i][j], 0, 0, 0);
    __syncthreads();
  }

  int rquad = (lane >> 4) * 4;
#pragma unroll
  for (int i = 0; i < 4; i++) {
    int mb = wm + i * 16 + rquad;
#pragma unroll
    for (int r = 0; r < 4; r++) {
      int m = mb + r;
      if (row0 + m < rows) {
        size_t hrow = (size_t)(beg + row0 + m) * SLAB;
#pragma unroll
        for (int j = 0; j < 4; j++) {
          int c = col0 + wn + j * 16 + lr;
          float v = acc[i][j][r] + b1[(size_t)e * DFF + slab * SLAB + c];
          h[hrow + c] = f2bf(fmaxf(v, 0.f));
        }
      }
    }
  }
}

// ---------------- MFMA GEMM2: out(+)= H_slab @ W2_slab, finalize on last slab ----------------
__global__ __launch_bounds__(256) void gemm2_kernel(
    const ushort_t* __restrict__ h, const ushort_t* __restrict__ W2T,
    const float* __restrict__ b2, const int* __restrict__ offsets,
    const int* __restrict__ perm, const float* __restrict__ wgt,
    float* __restrict__ out, int slab) {
  int e = blockIdx.z;
  int beg = offsets[e];
  int rows = offsets[e + 1] - beg;
  int row0 = blockIdx.y * BM;
  if (row0 >= rows) return;
  int col0 = blockIdx.x * BN;  // within DM

  __shared__ ushort_t As[BM * BKS];
  __shared__ ushort_t Bs[BN * BKS];
  __shared__ int toks[BM];

  int tid = threadIdx.x;
  if (tid < BM) {
    int r = row0 + tid;
    toks[tid] = (r < rows) ? perm[beg + r] : 0;
  }

  int wave = tid >> 6, lane = tid & 63;
  int wm = (wave & 1) * 64, wn = (wave >> 1) * 64;
  int lr = lane & 15;
  int kf = (lane >> 4) * 8;

  f32x4 acc[4][4] = {};

  const ushort_t* Ap = h + (size_t)(beg + row0) * SLAB;
  const ushort_t* Bp = W2T + ((size_t)e * DM + col0) * DFF + (size_t)slab * SLAB;

  for (int k0 = 0; k0 < SLAB; k0 += BKS) {
#pragma unroll
    for (int it = 0; it < 2; it++) {
      int idx = it * 256 + tid;
      int rr = idx >> 2, pp = idx & 3;
      async16(As + idx * 8, Ap + (size_t)rr * SLAB + k0 + pp * 8);
      async16(Bs + idx * 8, Bp + (size_t)rr * DFF + k0 + pp * 8);
    }
    __syncthreads();
    bf16x8 af[4], bfr[4];
#pragma unroll
    for (int i = 0; i < 4; i++)
      af[i] = *(const bf16x8*)(As + (wm + i * 16 + lr) * BKS + kf);
#pragma unroll
    for (int j = 0; j < 4; j++)
      bfr[j] = *(const bf16x8*)(Bs + (wn + j * 16 + lr) * BKS + kf);
#pragma unroll
    for (int i = 0; i < 4; i++)
#pragma unroll
      for (int j = 0; j < 4; j++)
        acc[i][j] = __builtin_amdgcn_mfma_f32_16x16x32_bf16(af[i], bfr[j], acc[i][j], 0, 0, 0);
    __syncthreads();
  }

  const bool first = (slab == 0);
  const bool last = (slab == NSLABS - 1);
  int rquad = (lane >> 4) * 4;
#pragma unroll
  for (int i = 0; i < 4; i++) {
    int mb = wm + i * 16 + rquad;
#pragma unroll
    for (int r = 0; r < 4; r++) {
      int m = mb + r;
      if (row0 + m < rows) {
        int tok = toks[m];
        float* orow = out + (size_t)tok * DM;
        float w = wgt[tok];
#pragma unroll
        for (int j = 0; j < 4; j++) {
          int c = col0 + wn + j * 16 + lr;
          float v = acc[i][j][r];
          if (!first) v += orow[c];
          if (last) v = (v + b2[(size_t)e * DM + c]) * w;
          orow[c] = v;
        }
      }
    }
  }
}

extern "C" void kernel_launch(void* const* d_in, const int* in_sizes, int n_in,
                              void* d_out, int out_size, void* d_ws, size_t ws_size,
                              hipStream_t stream) {
  (void)in_sizes; (void)n_in; (void)out_size; (void)ws_size;
  const float* x  = (const float*)d_in[0];
  const float* Wr = (const float*)d_in[1];
  const float* br = (const float*)d_in[2];
  const float* W1 = (const float*)d_in[3];
  const float* b1 = (const float*)d_in[4];
  const float* W2 = (const float*)d_in[5];
  const float* b2 = (const float*)d_in[6];
  float* out = (float*)d_out;

  char* ws = (char*)d_ws;
  int*   eidx    = (int*)(ws + 0);
  float* wgt     = (float*)(ws + 65536);
  int*   count   = (int*)(ws + 131072);
  int*   offsets = (int*)(ws + 131136);
  int*   cursor  = (int*)(ws + 131200);
  int*   perm    = (int*)(ws + 131328);
  ushort_t* xg   = (ushort_t*)(ws + 262144);                              // 33.55 MB
  ushort_t* W1T  = (ushort_t*)(ws + 262144 + 33554432);                   // 67.1 MB
  ushort_t* W2T  = (ushort_t*)(ws + 262144 + 33554432 + 67108864);        // 67.1 MB
  ushort_t* h    = (ushort_t*)(ws + 262144 + 33554432 + 2 * 67108864);    // (16384+128)*SLAB bf16

  hipMemsetAsync(count, 0, 32, stream);

  router_kernel<<<T_TOKENS / 4, 256, 0, stream>>>(x, Wr, br, eidx, wgt, count);
  scan_kernel<<<1, 64, 0, stream>>>(count, offsets, cursor);
  scatter_kernel<<<T_TOKENS / 256, 256, 0, stream>>>(eidx, cursor, perm);
  gather_x_kernel<<<T_TOKENS, 256, 0, stream>>>(x, perm, xg);
  convT_kernel<<<dim3(DFF / 64, DM / 64, NEXP), 256, 0, stream>>>(W1, W1T, DM, DFF);
  convT_kernel<<<dim3(DM / 64, DFF / 64, NEXP), 256, 0, stream>>>(W2, W2T, DFF, DM);

  for (int s = 0; s < NSLABS; s++) {
    gemm1_kernel<<<dim3(SLAB / BN, T_TOKENS / BM, NEXP), 256, 0, stream>>>(
        xg, W1T, b1, offsets, h, s);
    gemm2_kernel<<<dim3(DM / BN, T_TOKENS / BM, NEXP), 256, 0, stream>>>(
        h, W2T, b2, offsets, perm, wgt, out, s);
  }
}

// Round 3
// 1112.668 us; speedup vs baseline: 4.4530x; 1.1304x over previous
//
#include <hip/hip_runtime.h>
#include <hip/hip_bf16.h>

#define T_TOKENS 16384
#define DM 1024
#define DFF 4096
#define NEXP 8

#define BM 128
#define BN 128
#define BKS 32
#define NTILES 136

typedef unsigned short ushort_t;
typedef __attribute__((ext_vector_type(8))) __bf16 bf16x8;
typedef __attribute__((ext_vector_type(4))) float f32x4;

__device__ __forceinline__ void async16(void* lds, const void* g) {
  __builtin_amdgcn_global_load_lds(
      (__attribute__((address_space(1))) void*)(void*)g,
      (__attribute__((address_space(3))) void*)lds, 16, 0, 0);
}

__device__ __forceinline__ ushort_t f2bf(float f) {
  union { float f; unsigned u; } v;
  v.f = f;
  unsigned r = v.u + 0x7FFF + ((v.u >> 16) & 1);
  return (ushort_t)(r >> 16);
}

// ---------------- router: one wave per token ----------------
__global__ __launch_bounds__(256) void router_kernel(
    const float* __restrict__ x, const float* __restrict__ Wr,
    const float* __restrict__ br, int* __restrict__ eidx,
    float* __restrict__ wgt, int* __restrict__ count) {
  int wave = threadIdx.x >> 6;
  int lane = threadIdx.x & 63;
  int t = blockIdx.x * 4 + wave;
  if (t >= T_TOKENS) return;

  float acc[8];
#pragma unroll
  for (int e = 0; e < 8; e++) acc[e] = 0.f;

  const float* xr = x + (size_t)t * DM;
  for (int k = lane; k < DM; k += 64) {
    float xv = xr[k];
    const float4* w4 = (const float4*)(Wr + (size_t)k * 8);
    float4 w0 = w4[0];
    float4 w1 = w4[1];
    acc[0] += xv * w0.x; acc[1] += xv * w0.y;
    acc[2] += xv * w0.z; acc[3] += xv * w0.w;
    acc[4] += xv * w1.x; acc[5] += xv * w1.y;
    acc[6] += xv * w1.z; acc[7] += xv * w1.w;
  }
#pragma unroll
  for (int e = 0; e < 8; e++) {
#pragma unroll
    for (int m = 32; m > 0; m >>= 1) acc[e] += __shfl_xor(acc[e], m, 64);
  }
  if (lane == 0) {
    float lg[8];
    float mx = -1e30f;
#pragma unroll
    for (int e = 0; e < 8; e++) {
      lg[e] = acc[e] + br[e];
      mx = fmaxf(mx, lg[e]);
    }
    float s = 0.f;
#pragma unroll
    for (int e = 0; e < 8; e++) s += expf(lg[e] - mx);
    int am = 0;
    float best = lg[0];
#pragma unroll
    for (int e = 1; e < 8; e++) {
      if (lg[e] > best) { best = lg[e]; am = e; }
    }
    eidx[t] = am;
    wgt[t] = expf(best - mx) / s;
    atomicAdd(&count[am], 1);
  }
}

// ---------------- scan + dense tile table ----------------
__global__ void scan_kernel(const int* __restrict__ count, int* __restrict__ offsets,
                            int* __restrict__ cursor, int4* __restrict__ tiles) {
  if (threadIdx.x == 0) {
    int run = 0;
    for (int e = 0; e < NEXP; e++) {
      offsets[e] = run;
      cursor[e] = run;
      run += count[e];
    }
    offsets[NEXP] = run;
    int nt = 0;
    for (int e = 0; e < NEXP; e++) {
      int beg = offsets[e];
      int rows = offsets[e + 1] - beg;
      for (int r0 = 0; r0 < rows; r0 += BM) {
        tiles[nt] = make_int4(e, beg, rows, r0);
        nt++;
      }
    }
    for (; nt < NTILES; nt++) tiles[nt] = make_int4(-1, 0, 0, 0);
  }
}

// ---------------- scatter token ids into per-expert lists ----------------
__global__ __launch_bounds__(256) void scatter_kernel(
    const int* __restrict__ eidx, int* __restrict__ cursor, int* __restrict__ perm) {
  int t = blockIdx.x * 256 + threadIdx.x;
  if (t < T_TOKENS) {
    int e = eidx[t];
    int pos = atomicAdd(&cursor[e], 1);
    perm[pos] = t;
  }
}

// ---------------- gather x rows into expert order, fp32 -> bf16 ----------------
__global__ __launch_bounds__(256) void gather_x_kernel(
    const float* __restrict__ x, const int* __restrict__ perm,
    ushort_t* __restrict__ xg) {
  int g = blockIdx.x;
  int tok = perm[g];
  int tid = threadIdx.x;
  float4 v = ((const float4*)(x + (size_t)tok * DM))[tid];
  ushort4 o;
  o.x = f2bf(v.x); o.y = f2bf(v.y); o.z = f2bf(v.z); o.w = f2bf(v.w);
  ((ushort4*)(xg + (size_t)g * DM))[tid] = o;
}

// ---------------- transpose+convert: W [E][R][C] fp32 -> WT [E][C][R] bf16 ----------------
__global__ __launch_bounds__(256) void convT_kernel(
    const float* __restrict__ W, ushort_t* __restrict__ WT, int R, int C) {
  __shared__ float t[64][65];
  int e = blockIdx.z;
  int r0 = blockIdx.y << 6, c0 = blockIdx.x << 6;
  int tid = threadIdx.x;
  const float* Wp = W + (size_t)e * R * C;
#pragma unroll
  for (int i = 0; i < 4; i++) {
    int r = (tid >> 4) + i * 16;
    int c = (tid & 15) * 4;
    float4 v = *(const float4*)(Wp + (size_t)(r0 + r) * C + c0 + c);
    t[r][c] = v.x; t[r][c + 1] = v.y; t[r][c + 2] = v.z; t[r][c + 3] = v.w;
  }
  __syncthreads();
  ushort_t* Op = WT + (size_t)e * R * C;
#pragma unroll
  for (int i = 0; i < 4; i++) {
    int c = (tid >> 4) + i * 16;
    int r = (tid & 15) * 4;
    ushort4 o;
    o.x = f2bf(t[r][c]);
    o.y = f2bf(t[r + 1][c]);
    o.z = f2bf(t[r + 2][c]);
    o.w = f2bf(t[r + 3][c]);
    *(ushort4*)(Op + (size_t)(c0 + c) * R + r0 + r) = o;
  }
}

// ---------------- MFMA GEMM1: h_slab = relu(Xg @ W1 + b1) ----------------
__global__ __launch_bounds__(256) void gemm1_kernel(
    const ushort_t* __restrict__ xg, const ushort_t* __restrict__ W1T,
    const float* __restrict__ b1, const int4* __restrict__ tiles,
    ushort_t* __restrict__ h, int hld, int slabOff) {
  int4 tl = tiles[blockIdx.y];
  if (tl.x < 0) return;
  int e = tl.x, beg = tl.y, rows = tl.z, row0 = tl.w;
  int col0 = blockIdx.x * BN;       // within slab
  int gcol0 = slabOff + col0;       // within DFF

  __shared__ ushort_t As[BM * BKS];
  __shared__ ushort_t Bs[BN * BKS];

  int tid = threadIdx.x;
  int wave = tid >> 6, lane = tid & 63;
  int wm = (wave & 1) * 64, wn = (wave >> 1) * 64;
  int lr = lane & 15;
  int kf = (lane >> 4) * 8;

  f32x4 acc[4][4] = {};

  const ushort_t* Ap = xg + (size_t)(beg + row0) * DM;
  const ushort_t* Bp = W1T + ((size_t)e * DFF + gcol0) * DM;

  for (int k0 = 0; k0 < DM; k0 += BKS) {
#pragma unroll
    for (int it = 0; it < 2; it++) {
      int idx = it * 256 + tid;
      int rr = idx >> 2, pp = idx & 3;
      async16(As + idx * 8, Ap + (size_t)rr * DM + k0 + pp * 8);
      async16(Bs + idx * 8, Bp + (size_t)rr * DM + k0 + pp * 8);
    }
    __syncthreads();
    bf16x8 af[4], bfr[4];
#pragma unroll
    for (int i = 0; i < 4; i++)
      af[i] = *(const bf16x8*)(As + (wm + i * 16 + lr) * BKS + kf);
#pragma unroll
    for (int j = 0; j < 4; j++)
      bfr[j] = *(const bf16x8*)(Bs + (wn + j * 16 + lr) * BKS + kf);
#pragma unroll
    for (int i = 0; i < 4; i++)
#pragma unroll
      for (int j = 0; j < 4; j++)
        acc[i][j] = __builtin_amdgcn_mfma_f32_16x16x32_bf16(af[i], bfr[j], acc[i][j], 0, 0, 0);
    __syncthreads();
  }

  int rquad = (lane >> 4) * 4;
#pragma unroll
  for (int i = 0; i < 4; i++) {
    int mb = wm + i * 16 + rquad;
#pragma unroll
    for (int r = 0; r < 4; r++) {
      int m = mb + r;
      if (row0 + m < rows) {
        size_t hrow = (size_t)(beg + row0 + m) * hld;
#pragma unroll
        for (int j = 0; j < 4; j++) {
          int c = col0 + wn + j * 16 + lr;
          float v = acc[i][j][r] + b1[(size_t)e * DFF + slabOff + c];
          h[hrow + c] = f2bf(fmaxf(v, 0.f));
        }
      }
    }
  }
}

// ---------------- MFMA GEMM2: out(+)= H_slab @ W2_slab ----------------
__global__ __launch_bounds__(256) void gemm2_kernel(
    const ushort_t* __restrict__ h, const ushort_t* __restrict__ W2T,
    const float* __restrict__ b2, const int4* __restrict__ tiles,
    const int* __restrict__ perm, const float* __restrict__ wgt,
    float* __restrict__ out, int hld, int slabOff, int first, int last) {
  int4 tl = tiles[blockIdx.y];
  if (tl.x < 0) return;
  int e = tl.x, beg = tl.y, rows = tl.z, row0 = tl.w;
  int col0 = blockIdx.x * BN;  // within DM

  __shared__ ushort_t As[BM * BKS];
  __shared__ ushort_t Bs[BN * BKS];
  __shared__ int toks[BM];

  int tid = threadIdx.x;
  if (tid < BM) {
    int r = row0 + tid;
    toks[tid] = (r < rows) ? perm[beg + r] : 0;
  }

  int wave = tid >> 6, lane = tid & 63;
  int wm = (wave & 1) * 64, wn = (wave >> 1) * 64;
  int lr = lane & 15;
  int kf = (lane >> 4) * 8;

  f32x4 acc[4][4] = {};

  const ushort_t* Ap = h + (size_t)(beg + row0) * hld;
  const ushort_t* Bp = W2T + ((size_t)e * DM + col0) * DFF + slabOff;

  for (int k0 = 0; k0 < hld; k0 += BKS) {
#pragma unroll
    for (int it = 0; it < 2; it++) {
      int idx = it * 256 + tid;
      int rr = idx >> 2, pp = idx & 3;
      async16(As + idx * 8, Ap + (size_t)rr * hld + k0 + pp * 8);
      async16(Bs + idx * 8, Bp + (size_t)rr * DFF + k0 + pp * 8);
    }
    __syncthreads();
    bf16x8 af[4], bfr[4];
#pragma unroll
    for (int i = 0; i < 4; i++)
      af[i] = *(const bf16x8*)(As + (wm + i * 16 + lr) * BKS + kf);
#pragma unroll
    for (int j = 0; j < 4; j++)
      bfr[j] = *(const bf16x8*)(Bs + (wn + j * 16 + lr) * BKS + kf);
#pragma unroll
    for (int i = 0; i < 4; i++)
#pragma unroll
      for (int j = 0; j < 4; j++)
        acc[i][j] = __builtin_amdgcn_mfma_f32_16x16x32_bf16(af[i], bfr[j], acc[i][j], 0, 0, 0);
    __syncthreads();
  }

  int rquad = (lane >> 4) * 4;
#pragma unroll
  for (int i = 0; i < 4; i++) {
    int mb = wm + i * 16 + rquad;
#pragma unroll
    for (int r = 0; r < 4; r++) {
      int m = mb + r;
      if (row0 + m < rows) {
        int tok = toks[m];
        float* orow = out + (size_t)tok * DM;
        float w = wgt[tok];
#pragma unroll
        for (int j = 0; j < 4; j++) {
          int c = col0 + wn + j * 16 + lr;
          float v = acc[i][j][r];
          if (!first) v += orow[c];
          if (last) v = (v + b2[(size_t)e * DM + c]) * w;
          orow[c] = v;
        }
      }
    }
  }
}

extern "C" void kernel_launch(void* const* d_in, const int* in_sizes, int n_in,
                              void* d_out, int out_size, void* d_ws, size_t ws_size,
                              hipStream_t stream) {
  (void)in_sizes; (void)n_in; (void)out_size;
  const float* x  = (const float*)d_in[0];
  const float* Wr = (const float*)d_in[1];
  const float* br = (const float*)d_in[2];
  const float* W1 = (const float*)d_in[3];
  const float* b1 = (const float*)d_in[4];
  const float* W2 = (const float*)d_in[5];
  const float* b2 = (const float*)d_in[6];
  float* out = (float*)d_out;

  char* ws = (char*)d_ws;
  int*   eidx    = (int*)(ws + 0);
  float* wgt     = (float*)(ws + 65536);
  int*   count   = (int*)(ws + 131072);
  int*   offsets = (int*)(ws + 131136);
  int*   cursor  = (int*)(ws + 131264);
  int4*  tiles   = (int4*)(ws + 131392);   // 136 * 16 B
  int*   perm    = (int*)(ws + 135168);    // 64 KB

  size_t XG_BYTES = (size_t)(T_TOKENS + BM) * DM * sizeof(ushort_t);  // padded
  ushort_t* xg  = (ushort_t*)(ws + 262144);
  ushort_t* W1T = (ushort_t*)(ws + 262144 + XG_BYTES);
  ushort_t* W2T = (ushort_t*)(ws + 262144 + XG_BYTES + 67108864);
  size_t hoff = 262144 + XG_BYTES + 2ull * 67108864;
  ushort_t* h   = (ushort_t*)(ws + hoff);

  // single-slab (K=DFF) if workspace allows the full padded h, else 2 slabs
  size_t need1 = hoff + (size_t)(T_TOKENS + BM) * DFF * sizeof(ushort_t);
  int slabW = (ws_size >= need1) ? DFF : (DFF / 2);
  int nslab = DFF / slabW;

  hipMemsetAsync(count, 0, 32, stream);

  router_kernel<<<T_TOKENS / 4, 256, 0, stream>>>(x, Wr, br, eidx, wgt, count);
  scan_kernel<<<1, 64, 0, stream>>>(count, offsets, cursor, tiles);
  scatter_kernel<<<T_TOKENS / 256, 256, 0, stream>>>(eidx, cursor, perm);
  gather_x_kernel<<<T_TOKENS, 256, 0, stream>>>(x, perm, xg);
  convT_kernel<<<dim3(DFF / 64, DM / 64, NEXP), 256, 0, stream>>>(W1, W1T, DM, DFF);
  convT_kernel<<<dim3(DM / 64, DFF / 64, NEXP), 256, 0, stream>>>(W2, W2T, DFF, DM);

  for (int s = 0; s < nslab; s++) {
    gemm1_kernel<<<dim3(slabW / BN, NTILES), 256, 0, stream>>>(
        xg, W1T, b1, tiles, h, slabW, s * slabW);
    gemm2_kernel<<<dim3(DM / BN, NTILES), 256, 0, stream>>>(
        h, W2T, b2, tiles, perm, wgt, out, slabW, s * slabW,
        (s == 0) ? 1 : 0, (s == nslab - 1) ? 1 : 0);
  }
}